// Round 7
// baseline (447.717 us; speedup 1.0000x reference)
//
#include <hip/hip_runtime.h>
#include <hip/hip_bf16.h>
#include <stdint.h>

#define L_ 25
#define E_ 64
#define H_ 8
#define B_ 1000
#define S_ 512
#define GQ 4                       // batch elements per block
#define NCELL (L_ * GQ)            // 100 cells per block
#define NPT 2                      // batch chains per THREAD (ILP-2)
#define TPBR (L_ * (GQ / NPT) * 8) // 400 threads, thread = (l, gh, j)
#define TS 4                       // timesteps per superstep
#define NSUPER (S_ / TS + L_ - 1)  // 152 supersteps
#define HS 12                      // per-cell stride hsh/hrsh: 48B, banks disjoint
#define XG 36                      // per-cell stride xbuf: 144B (16B-aligned)

typedef float v2f __attribute__((ext_vector_type(2)));
typedef float v4f __attribute__((ext_vector_type(4)));

#define PIN(x) asm volatile("" : "+v"(x))

// v_pk_fma_f32: {a.x*b.x+c.x, a.y*b.y+c.y}
__device__ __forceinline__ v2f pkfma(v2f a, v2f b, v2f c) {
  v2f d;
  asm("v_pk_fma_f32 %0, %1, %2, %3" : "=v"(d) : "v"(a), "v"(b), "v"(c));
  return d;
}
// op_sel broadcast of a.x: {a.x*b.x+c.x, a.x*b.y+c.y}
__device__ __forceinline__ v2f pkfma_l(v2f a, v2f b, v2f c) {
  v2f d;
  asm("v_pk_fma_f32 %0, %1, %2, %3 op_sel:[0,0,0] op_sel_hi:[0,1,1]"
      : "=v"(d) : "v"(a), "v"(b), "v"(c));
  return d;
}
// op_sel broadcast of a.y: {a.y*b.x+c.x, a.y*b.y+c.y}
__device__ __forceinline__ v2f pkfma_h(v2f a, v2f b, v2f c) {
  v2f d;
  asm("v_pk_fma_f32 %0, %1, %2, %3 op_sel:[1,0,0] op_sel_hi:[1,1,1]"
      : "=v"(d) : "v"(a), "v"(b), "v"(c));
  return d;
}
__device__ __forceinline__ v2f pkadd(v2f a, v2f b) {
  v2f d;
  asm("v_pk_add_f32 %0, %1, %2" : "=v"(d) : "v"(a), "v"(b));
  return d;
}
__device__ __forceinline__ v2f vlo(v4f v) { return __builtin_shufflevector(v, v, 0, 1); }
__device__ __forceinline__ v2f vhi(v4f v) { return __builtin_shufflevector(v, v, 2, 3); }
__device__ __forceinline__ v2f mk2(float a, float b) { v2f r; r.x = a; r.y = b; return r; }

// zr chain over 8 k's: acc.{x=z,y=r} += sum_k m[k] * {Wz,Wr}[k]
#define CHAIN8(acc, ma, mb, w)            \
  acc = pkfma_l(vlo(ma), w[0], acc);      \
  acc = pkfma_h(vlo(ma), w[1], acc);      \
  acc = pkfma_l(vhi(ma), w[2], acc);      \
  acc = pkfma_h(vhi(ma), w[3], acc);      \
  acc = pkfma_l(vlo(mb), w[4], acc);      \
  acc = pkfma_h(vlo(mb), w[5], acc);      \
  acc = pkfma_l(vhi(mb), w[6], acc);      \
  acc = pkfma_h(vhi(mb), w[7], acc);

// element-wise paired chain: acc += {m[2q]*w[q].x, m[2q+1]*w[q].y}
#define CHAIN4P(acc, ma, mb, w)           \
  acc = pkfma(vlo(ma), w[0], acc);        \
  acc = pkfma(vhi(ma), w[1], acc);        \
  acc = pkfma(vlo(mb), w[2], acc);        \
  acc = pkfma(vhi(mb), w[3], acc);

__device__ __forceinline__ float ulo(uint32_t u) { return __uint_as_float(u << 16); }
__device__ __forceinline__ float uhi(uint32_t u) { return __uint_as_float(u & 0xffff0000u); }

__device__ __forceinline__ float toF(float v) { return v; }
__device__ __forceinline__ float toF(__hip_bfloat16 v) { return __bfloat162float(v); }
__device__ __forceinline__ void stP(float* p, float v) { *p = v; }
__device__ __forceinline__ void stP(__hip_bfloat16* p, float v) { *p = __float2bfloat16(v); }

__device__ __forceinline__ v2f loadC2(const float* p) { return *(const v2f*)p; }
__device__ __forceinline__ v2f loadC2(const __hip_bfloat16* p) {
  const uint32_t u = *(const uint32_t*)p;
  return mk2(ulo(u), uhi(u));
}

__device__ __forceinline__ void load8f(const __hip_bfloat16* p, float* o) {
  const uint4 v = *(const uint4*)p;
  o[0] = ulo(v.x); o[1] = uhi(v.x); o[2] = ulo(v.y); o[3] = uhi(v.y);
  o[4] = ulo(v.z); o[5] = uhi(v.z); o[6] = ulo(v.w); o[7] = uhi(v.w);
}
__device__ __forceinline__ void load8f(const float* p, float* o) {
  const float4 a = ((const float4*)p)[0];
  const float4 b = ((const float4*)p)[1];
  o[0] = a.x; o[1] = a.y; o[2] = a.z; o[3] = a.w;
  o[4] = b.x; o[5] = b.y; o[6] = b.z; o[7] = b.w;
}

__device__ __forceinline__ void st4(float* p, float a, float b, float c, float d) {
  float4 v; v.x = a; v.y = b; v.z = c; v.w = d;
  *(float4*)p = v;
}
__device__ __forceinline__ void st4(__hip_bfloat16* p, float a, float b, float c, float d) {
  __hip_bfloat16 t[4] = {__float2bfloat16(a), __float2bfloat16(b),
                         __float2bfloat16(c), __float2bfloat16(d)};
  *(ushort4*)p = *(ushort4*)t;
}

__device__ __forceinline__ float sigmo(float x) {
  return __builtin_amdgcn_rcpf(1.f + __expf(-x));
}

// Per-block dtype probe: max |bf16| of first 256 shorts of emb.
__device__ __forceinline__ void detect64(const unsigned short* __restrict__ u,
                                         int tid, float* fl) {
  if (tid < 64) {
    float m = 0.f;
#pragma unroll
    for (int k = 0; k < 4; ++k) {
      const uint32_t q = u[tid * 4 + k];
      float v = fabsf(__uint_as_float(q << 16));
      if (!(v < 1e30f)) v = 1e30f;
      m = fmaxf(m, v);
    }
#pragma unroll
    for (int off = 32; off; off >>= 1) m = fmaxf(m, __shfl_down(m, off, 64));
    if (tid == 0) *fl = (m > 2.0f) ? 0.f : 1.f;
  }
}

// ---------------------------------------------------------------------------
// Kernel 1: layer-0 x-projections. pre token layout (24 floats):
// [2j]={z_j}, [2j+1]={r_j}, [16+j]={h_j}.
// ---------------------------------------------------------------------------
template <typename T, typename PT>
__device__ __forceinline__ void pre_body(
    const int* __restrict__ x, const void* __restrict__ embv,
    const void* __restrict__ Wzv, const void* __restrict__ Wrv,
    const void* __restrict__ Whv, PT* __restrict__ pre,
    float* WL, float* TBb) {
  const T* emb = (const T*)embv;
  const T* Wz = (const T*)Wzv;
  const T* Wr = (const T*)Wrv;
  const T* Wh = (const T*)Whv;
  const int tid = threadIdx.x;

  for (int idx = tid; idx < 64 * 24; idx += 256) {
    const int k = idx / 24, c = idx - k * 24;
    float w;
    if (c < 16) w = toF(((c & 1) ? Wr : Wz)[k * 8 + (c >> 1)]);
    else        w = toF(Wh[k * 8 + (c - 16)]);
    WL[idx] = w;
  }
  __syncthreads();

  const int tok = blockIdx.x * 256 + tid;
  const int t = x[tok];

  v2f acc[12];
#pragma unroll
  for (int q = 0; q < 12; ++q) acc[q] = mk2(0.f, 0.f);

  for (int kb = 0; kb < 8; ++kb) {
    float e[8];
    load8f(emb + (size_t)t * E_ + kb * 8, e);
#pragma unroll
    for (int k8 = 0; k8 < 8; ++k8) {
      const v4f* wr = (const v4f*)(WL + (kb * 8 + k8) * 24);
      const v2f ee = mk2(e[k8], e[k8]);
#pragma unroll
      for (int q = 0; q < 6; ++q) {
        const v4f w4 = wr[q];
        acc[2 * q]     = pkfma(ee, vlo(w4), acc[2 * q]);
        acc[2 * q + 1] = pkfma(ee, vhi(w4), acc[2 * q + 1]);
      }
    }
  }

  // in-wave transpose: [24][65] per wave, conflict-free
  const int wid = tid >> 6, lane = tid & 63;
  float* tb = TBb + wid * (24 * 65);
#pragma unroll
  for (int q = 0; q < 12; ++q) {
    tb[(2 * q) * 65 + lane] = acc[q].x;
    tb[(2 * q + 1) * 65 + lane] = acc[q].y;
  }
  asm volatile("s_waitcnt lgkmcnt(0)" ::: "memory");
  __builtin_amdgcn_wave_barrier();

  PT* ob = pre + (size_t)(blockIdx.x * 256 + wid * 64) * 24;
#pragma unroll
  for (int it = 0; it < 6; ++it) {
    const int F0 = it * 256 + lane * 4;
    float o[4];
#pragma unroll
    for (int e2 = 0; e2 < 4; ++e2) {
      const int F = F0 + e2;
      const int tk = F / 24;
      const int c = F - tk * 24;
      o[e2] = tb[c * 65 + tk];
    }
    st4(ob + F0, o[0], o[1], o[2], o[3]);
  }
}

template <typename PT>
__global__ __launch_bounds__(256, 4) void gru_pre(
    const int* __restrict__ x, const void* __restrict__ emb,
    const void* __restrict__ Wz, const void* __restrict__ Wr,
    const void* __restrict__ Wh, PT* __restrict__ pre) {
  __shared__ __align__(16) float WL[64 * 24];
  __shared__ __align__(16) float TB[4][24 * 65];
  __shared__ float fl;
  detect64((const unsigned short*)emb, threadIdx.x, &fl);
  __syncthreads();
  if (fl != 0.f) pre_body<__hip_bfloat16, PT>(x, emb, Wz, Wr, Wh, pre, WL, &TB[0][0]);
  else           pre_body<float, PT>(x, emb, Wz, Wr, Wh, pre, WL, &TB[0][0]);
}

// ---------------------------------------------------------------------------
// One GRU timestep for BOTH of this thread's batch chains (ILP-2): the two
// dataflows are independent, so every ds round-trip / trans latency in one
// chain is covered by the other chain's instructions (in-order issue).
// Fused z/tanh update (one rcp per chain), identical FP order to R5.
// ---------------------------------------------------------------------------
#define TIMESTEP2(hp0, hp1, ax0_, ah0_, ax1_, ah1_, slotT, hn0_, hn1_)   \
  {                                                                      \
    const v4f ha01 = ((const v4f*)hgw0)[0];                              \
    const v4f ha23 = ((const v4f*)hgw0)[1];                              \
    const v4f hb01 = ((const v4f*)hgw1)[0];                              \
    const v4f hb23 = ((const v4f*)hgw1)[1];                              \
    v2f azrh0 = bzr;                                                     \
    CHAIN8(azrh0, ha01, ha23, wzrh);                                     \
    v2f azrh1 = bzr;                                                     \
    CHAIN8(azrh1, hb01, hb23, wzrh);                                     \
    const v2f azr0 = pkadd(azrh0, ax0_);                                 \
    const v2f azr1 = pkadd(azrh1, ax1_);                                 \
    const float r0_ = sigmo(azr0.y);                                     \
    const float r1_ = sigmo(azr1.y);                                     \
    *hrg0j = (hp0) * r0_;                                                \
    *hrg1j = (hp1) * r1_;                                                \
    __builtin_amdgcn_wave_barrier();                                     \
    const v4f ra01 = ((const v4f*)hrg0)[0];                              \
    const v4f ra23 = ((const v4f*)hrg0)[1];                              \
    const v4f rb01 = ((const v4f*)hrg1)[0];                              \
    const v4f rb23 = ((const v4f*)hrg1)[1];                              \
    CHAIN4P(ah0_, ra01, ra23, wrh2);                                     \
    CHAIN4P(ah1_, rb01, rb23, wrh2);                                     \
    const float aha_ = ah0_.x + ah0_.y;                                  \
    const float ahb_ = ah1_.x + ah1_.y;                                  \
    const float ez0_ = __expf(fminf(-azr0.x, 30.f));                     \
    const float eh0_ = __expf(fminf(-2.f * aha_, 30.f));                 \
    const float ez1_ = __expf(fminf(-azr1.x, 30.f));                     \
    const float eh1_ = __expf(fminf(-2.f * ahb_, 30.f));                 \
    const float t0_ = (hp0) * ez0_;                                      \
    const float t1_ = (hp1) * ez1_;                                      \
    const float nu0_ = fmaf(eh0_, t0_ - 1.f, t0_ + 1.f);                 \
    const float nu1_ = fmaf(eh1_, t1_ - 1.f, t1_ + 1.f);                 \
    const float de0_ = (1.f + ez0_) * (1.f + eh0_);                      \
    const float de1_ = (1.f + ez1_) * (1.f + eh1_);                      \
    hn0_ = nu0_ * __builtin_amdgcn_rcpf(de0_);                           \
    hn1_ = nu1_ * __builtin_amdgcn_rcpf(de1_);                           \
    *hgw0j = hn0_;                                                       \
    *hgw1j = hn1_;                                                       \
    xc0[(slotT) * 8 + j] = hn0_;                                         \
    xc1[(slotT) * 8 + j] = hn1_;                                         \
    __builtin_amdgcn_wave_barrier();                                     \
  }

// ---------------------------------------------------------------------------
// Kernel 2: pipelined recurrence, TS=4, global __syncthreads (hang-proof),
// NPT=2 batch chains per thread. 400 threads (7 waves), 250 blocks.
// Thread (l, gh, j) owns cells (l, gh) and (l, gh+2); weights shared.
// Superstep s: layer l does t = 4(s-l) .. 4(s-l)+3 for both chains.
// ---------------------------------------------------------------------------
template <typename T, typename PT>
__device__ __forceinline__ void rec_body(
    const PT* __restrict__ pre,
    const void* __restrict__ Whz0v, const void* __restrict__ bz0v,
    const void* __restrict__ Whr0v, const void* __restrict__ br0v,
    const void* __restrict__ WrH0v, const void* __restrict__ bH0v,
    const void* __restrict__ Wxzv, const void* __restrict__ Whzv,
    const void* __restrict__ bzv, const void* __restrict__ Wxrv,
    const void* __restrict__ Whrv, const void* __restrict__ brv,
    const void* __restrict__ WxHv, const void* __restrict__ WrHv,
    const void* __restrict__ bHv, const void* __restrict__ Whyv,
    const void* __restrict__ byv, void* __restrict__ outv,
    float* hsh, float* hrsh, float* xbuf) {
  const T* Whz0 = (const T*)Whz0v; const T* bz0 = (const T*)bz0v;
  const T* Whr0 = (const T*)Whr0v; const T* br0 = (const T*)br0v;
  const T* WrH0 = (const T*)WrH0v; const T* bH0 = (const T*)bH0v;
  const T* Wxz = (const T*)Wxzv;   const T* Whz = (const T*)Whzv;
  const T* bz = (const T*)bzv;     const T* Wxr = (const T*)Wxrv;
  const T* Whr = (const T*)Whrv;   const T* br = (const T*)brv;
  const T* WxH = (const T*)WxHv;   const T* WrH = (const T*)WrHv;
  const T* bH = (const T*)bHv;     const T* Why = (const T*)Whyv;
  const T* by = (const T*)byv;     T* out = (T*)outv;

  const int tid = threadIdx.x;
  const int slot = tid >> 3;    // l*2 + gh, 0..49
  const int j = tid & 7;
  const int l = slot >> 1;
  const int gh = slot & 1;
  const int gi0 = l * GQ + gh;      // chain-0 cell
  const int gi1 = gi0 + 2;          // chain-1 cell
  const int b0 = blockIdx.x * GQ + gh;
  const int b1 = b0 + 2;

  for (int i = tid; i < NCELL * HS; i += TPBR) { hsh[i] = 0.f; hrsh[i] = 0.f; }
  for (int i = tid; i < 2 * NCELL * XG; i += TPBR) xbuf[i] = 0.f;  // l==0 x-reads dead

  // ---- weights (shared by both chains): z,r packed; H-gate k-paired ----
  v2f wzrx[8], wzrh[8], wxh2[4], wrh2[4], bzr;
  float vbh;
  if (l == 0) {
#pragma unroll
    for (int k = 0; k < 8; ++k) {
      wzrh[k] = mk2(toF(Whz0[k * 8 + j]), toF(Whr0[k * 8 + j]));
      wzrx[k] = mk2(0.f, 0.f);
    }
#pragma unroll
    for (int q = 0; q < 4; ++q) {
      wrh2[q] = mk2(toF(WrH0[(2 * q) * 8 + j]), toF(WrH0[(2 * q + 1) * 8 + j]));
      wxh2[q] = mk2(0.f, 0.f);
    }
    bzr = mk2(toF(bz0[j]), toF(br0[j]));
    vbh = toF(bH0[j]);
  } else {
    const int base = (l - 1) * 64;
#pragma unroll
    for (int k = 0; k < 8; ++k) {
      wzrx[k] = mk2(toF(Wxz[base + k * 8 + j]), toF(Wxr[base + k * 8 + j]));
      wzrh[k] = mk2(toF(Whz[base + k * 8 + j]), toF(Whr[base + k * 8 + j]));
    }
#pragma unroll
    for (int q = 0; q < 4; ++q) {
      wxh2[q] = mk2(toF(WxH[base + (2 * q) * 8 + j]), toF(WxH[base + (2 * q + 1) * 8 + j]));
      wrh2[q] = mk2(toF(WrH[base + (2 * q) * 8 + j]), toF(WrH[base + (2 * q + 1) * 8 + j]));
    }
    bzr = mk2(toF(bz[(l - 1) * 8 + j]), toF(br[(l - 1) * 8 + j]));
    vbh = toF(bH[(l - 1) * 8 + j]);
  }
#pragma unroll
  for (int k = 0; k < 8; ++k) { PIN(wzrx[k]); PIN(wzrh[k]); }
#pragma unroll
  for (int q = 0; q < 4; ++q) { PIN(wxh2[q]); PIN(wrh2[q]); }
  PIN(bzr); PIN(vbh);

  // layer-0 precomputed x-projections, both chains, 4 timesteps each
  const PT* ppr0 = pre + (size_t)b0 * (S_ * 24);
  const PT* ppr1 = pre + (size_t)b1 * (S_ * 24);
  v2f czr00 = mk2(0.f, 0.f), czr01 = czr00, czr02 = czr00, czr03 = czr00;
  v2f czr10 = czr00, czr11 = czr00, czr12 = czr00, czr13 = czr00;
  float ch00 = 0.f, ch01 = 0.f, ch02 = 0.f, ch03 = 0.f;
  float ch10 = 0.f, ch11 = 0.f, ch12 = 0.f, ch13 = 0.f;
  if (l == 0) {
    czr00 = loadC2(ppr0 + 0 * 24 + 2 * j);  ch00 = toF(ppr0[0 * 24 + 16 + j]);
    czr01 = loadC2(ppr0 + 1 * 24 + 2 * j);  ch01 = toF(ppr0[1 * 24 + 16 + j]);
    czr02 = loadC2(ppr0 + 2 * 24 + 2 * j);  ch02 = toF(ppr0[2 * 24 + 16 + j]);
    czr03 = loadC2(ppr0 + 3 * 24 + 2 * j);  ch03 = toF(ppr0[3 * 24 + 16 + j]);
    czr10 = loadC2(ppr1 + 0 * 24 + 2 * j);  ch10 = toF(ppr1[0 * 24 + 16 + j]);
    czr11 = loadC2(ppr1 + 1 * 24 + 2 * j);  ch11 = toF(ppr1[1 * 24 + 16 + j]);
    czr12 = loadC2(ppr1 + 2 * 24 + 2 * j);  ch12 = toF(ppr1[2 * 24 + 16 + j]);
    czr13 = loadC2(ppr1 + 3 * 24 + 2 * j);  ch13 = toF(ppr1[3 * 24 + 16 + j]);
  }

  float* hgw0 = hsh + gi0 * HS;
  float* hgw1 = hsh + gi1 * HS;
  float* hrg0 = hrsh + gi0 * HS;
  float* hrg1 = hrsh + gi1 * HS;
  float* hgw0j = hgw0 + j;
  float* hgw1j = hgw1 + j;
  float* hrg0j = hrg0 + j;
  float* hrg1j = hrg1 + j;
  const int gp0 = (gi0 >= GQ) ? (gi0 - GQ) * XG : 0;
  const int gp1 = (gi1 >= GQ) ? (gi1 - GQ) * XG : 0;
  const float* xpe0 = xbuf + NCELL * XG + gp0;  // read when s even
  const float* xpo0 = xbuf + gp0;               // read when s odd
  const float* xpe1 = xbuf + NCELL * XG + gp1;
  const float* xpo1 = xbuf + gp1;
  float* xce0 = xbuf + gi0 * XG;                // write when s even
  float* xco0 = xbuf + NCELL * XG + gi0 * XG;   // write when s odd
  float* xce1 = xbuf + gi1 * XG;
  float* xco1 = xbuf + NCELL * XG + gi1 * XG;

  float hown0 = 0.f, hown1 = 0.f;

  __syncthreads();

  for (int s = 0; s < NSUPER; ++s) {
    const unsigned rel = (unsigned)(s - l);
    if (rel < (unsigned)(S_ / TS)) {
      const float* xp0 = (s & 1) ? xpo0 : xpe0;
      const float* xp1 = (s & 1) ? xpo1 : xpe1;
      float* xc0 = (s & 1) ? xco0 : xce0;
      float* xc1 = (s & 1) ? xco1 : xce1;

      // T0,T1 x-tiles, both chains
      const v4f c0t0a = ((const v4f*)xp0)[0];
      const v4f c0t0b = ((const v4f*)xp0)[1];
      const v4f c0t1a = ((const v4f*)xp0)[2];
      const v4f c0t1b = ((const v4f*)xp0)[3];
      const v4f c1t0a = ((const v4f*)xp1)[0];
      const v4f c1t0b = ((const v4f*)xp1)[1];
      const v4f c1t1a = ((const v4f*)xp1)[2];
      const v4f c1t1b = ((const v4f*)xp1)[3];

      // l==0 global prefetch of next superstep, both chains (vmcnt-hidden)
      v2f nzr00 = mk2(0.f, 0.f), nzr01 = nzr00, nzr02 = nzr00, nzr03 = nzr00;
      v2f nzr10 = nzr00, nzr11 = nzr00, nzr12 = nzr00, nzr13 = nzr00;
      float nh00 = 0.f, nh01 = 0.f, nh02 = 0.f, nh03 = 0.f;
      float nh10 = 0.f, nh11 = 0.f, nh12 = 0.f, nh13 = 0.f;
      const bool pf = (l == 0) && (rel + 1u < (unsigned)(S_ / TS));
      if (pf) {
        const PT* pn0 = ppr0 + (TS * rel + 4) * 24;
        const PT* pn1 = ppr1 + (TS * rel + 4) * 24;
        nzr00 = loadC2(pn0 + 0 * 24 + 2 * j);  nh00 = toF(pn0[0 * 24 + 16 + j]);
        nzr01 = loadC2(pn0 + 1 * 24 + 2 * j);  nh01 = toF(pn0[1 * 24 + 16 + j]);
        nzr02 = loadC2(pn0 + 2 * 24 + 2 * j);  nh02 = toF(pn0[2 * 24 + 16 + j]);
        nzr03 = loadC2(pn0 + 3 * 24 + 2 * j);  nh03 = toF(pn0[3 * 24 + 16 + j]);
        nzr10 = loadC2(pn1 + 0 * 24 + 2 * j);  nh10 = toF(pn1[0 * 24 + 16 + j]);
        nzr11 = loadC2(pn1 + 1 * 24 + 2 * j);  nh11 = toF(pn1[1 * 24 + 16 + j]);
        nzr12 = loadC2(pn1 + 2 * 24 + 2 * j);  nh12 = toF(pn1[2 * 24 + 16 + j]);
        nzr13 = loadC2(pn1 + 3 * 24 + 2 * j);  nh13 = toF(pn1[3 * 24 + 16 + j]);
      }

      // x-side chains T0,T1 (independent filler for T0's stalls)
      v2f ax00 = czr00; CHAIN8(ax00, c0t0a, c0t0b, wzrx);
      v2f ah00 = mk2(ch00, vbh); CHAIN4P(ah00, c0t0a, c0t0b, wxh2);
      v2f ax10 = czr10; CHAIN8(ax10, c1t0a, c1t0b, wzrx);
      v2f ah10 = mk2(ch10, vbh); CHAIN4P(ah10, c1t0a, c1t0b, wxh2);
      v2f ax01 = czr01; CHAIN8(ax01, c0t1a, c0t1b, wzrx);
      v2f ah01 = mk2(ch01, vbh); CHAIN4P(ah01, c0t1a, c0t1b, wxh2);
      v2f ax11 = czr11; CHAIN8(ax11, c1t1a, c1t1b, wzrx);
      v2f ah11 = mk2(ch11, vbh); CHAIN4P(ah11, c1t1a, c1t1b, wxh2);

      float hn00, hn01, hn02, hn03, hn10, hn11, hn12, hn13;
      TIMESTEP2(hown0, hown1, ax00, ah00, ax10, ah10, 0, hn00, hn10);

      // T2,T3 x-tiles + chains (filler for T1's stalls)
      const v4f c0t2a = ((const v4f*)xp0)[4];
      const v4f c0t2b = ((const v4f*)xp0)[5];
      const v4f c0t3a = ((const v4f*)xp0)[6];
      const v4f c0t3b = ((const v4f*)xp0)[7];
      const v4f c1t2a = ((const v4f*)xp1)[4];
      const v4f c1t2b = ((const v4f*)xp1)[5];
      const v4f c1t3a = ((const v4f*)xp1)[6];
      const v4f c1t3b = ((const v4f*)xp1)[7];
      v2f ax02 = czr02; CHAIN8(ax02, c0t2a, c0t2b, wzrx);
      v2f ah02 = mk2(ch02, vbh); CHAIN4P(ah02, c0t2a, c0t2b, wxh2);
      v2f ax12 = czr12; CHAIN8(ax12, c1t2a, c1t2b, wzrx);
      v2f ah12 = mk2(ch12, vbh); CHAIN4P(ah12, c1t2a, c1t2b, wxh2);
      v2f ax03 = czr03; CHAIN8(ax03, c0t3a, c0t3b, wzrx);
      v2f ah03 = mk2(ch03, vbh); CHAIN4P(ah03, c0t3a, c0t3b, wxh2);
      v2f ax13 = czr13; CHAIN8(ax13, c1t3a, c1t3b, wzrx);
      v2f ah13 = mk2(ch13, vbh); CHAIN4P(ah13, c1t3a, c1t3b, wxh2);

      TIMESTEP2(hn00, hn10, ax01, ah01, ax11, ah11, 1, hn01, hn11);
      TIMESTEP2(hn01, hn11, ax02, ah02, ax12, ah12, 2, hn02, hn12);
      TIMESTEP2(hn02, hn12, ax03, ah03, ax13, ah13, 3, hn03, hn13);

      hown0 = hn03; hown1 = hn13;
      czr00 = nzr00; ch00 = nh00; czr01 = nzr01; ch01 = nh01;
      czr02 = nzr02; ch02 = nh02; czr03 = nzr03; ch03 = nh03;
      czr10 = nzr10; ch10 = nh10; czr11 = nzr11; ch11 = nh11;
      czr12 = nzr12; ch12 = nh12; czr13 = nzr13; ch13 = nh13;
    }
    __syncthreads();
  }

  // ---- epilogue ----
  stP(out + B_ + (l * B_ + b0) * H_ + j, hown0);
  stP(out + B_ + (l * B_ + b1) * H_ + j, hown1);
  if (l == L_ - 1 && j == 0) {
    float s0 = toF(by[0]), s1 = toF(by[0]);
#pragma unroll
    for (int k = 0; k < 8; ++k) {
      const float wyk = toF(Why[k]);
      s0 = fmaf(hgw0[k], wyk, s0);
      s1 = fmaf(hgw1[k], wyk, s1);
    }
    stP(out + b0, s0);
    stP(out + b1, s1);
  }
}

template <typename PT>
__global__ __launch_bounds__(TPBR) void gru_rec(
    const void* __restrict__ emb, const PT* __restrict__ pre,
    const void* __restrict__ Whz0, const void* __restrict__ bz0,
    const void* __restrict__ Whr0, const void* __restrict__ br0,
    const void* __restrict__ WrH0, const void* __restrict__ bH0,
    const void* __restrict__ Wxz, const void* __restrict__ Whz,
    const void* __restrict__ bz, const void* __restrict__ Wxr,
    const void* __restrict__ Whr, const void* __restrict__ br,
    const void* __restrict__ WxH, const void* __restrict__ WrH,
    const void* __restrict__ bH, const void* __restrict__ Why,
    const void* __restrict__ by, void* __restrict__ out) {
  __shared__ __align__(16) float hsh[NCELL * HS];
  __shared__ __align__(16) float hrsh[NCELL * HS];
  __shared__ __align__(16) float xbuf[2 * NCELL * XG];
  __shared__ float fl;
  detect64((const unsigned short*)emb, threadIdx.x, &fl);
  __syncthreads();
  if (fl != 0.f)
    rec_body<__hip_bfloat16, PT>(pre, Whz0, bz0, Whr0, br0, WrH0, bH0, Wxz, Whz,
                                 bz, Wxr, Whr, br, WxH, WrH, bH, Why, by, out,
                                 hsh, hrsh, xbuf);
  else
    rec_body<float, PT>(pre, Whz0, bz0, Whr0, br0, WrH0, bH0, Wxz, Whz, bz, Wxr,
                        Whr, br, WxH, WrH, bH, Why, by, out, hsh, hrsh, xbuf);
}

// ---------------------------------------------------------------------------
template <typename PT>
static void launch_all(void* const* d_in, PT* pre, void* d_out, hipStream_t stream) {
  gru_pre<PT><<<B_ * S_ / 256, 256, 0, stream>>>(
      (const int*)d_in[0], d_in[1], d_in[2], d_in[5], d_in[8], pre);
  gru_rec<PT><<<B_ / GQ, TPBR, 0, stream>>>(
      d_in[1], pre, d_in[3], d_in[4], d_in[6], d_in[7], d_in[9], d_in[10],
      d_in[11], d_in[12], d_in[13], d_in[14], d_in[15], d_in[16], d_in[17],
      d_in[18], d_in[19], d_in[20], d_in[21], d_out);
}

extern "C" void kernel_launch(void* const* d_in, const int* in_sizes, int n_in,
                              void* d_out, int out_size, void* d_ws, size_t ws_size,
                              hipStream_t stream) {
  const size_t needF = (size_t)B_ * S_ * 24 * sizeof(float);
  if (ws_size >= needF)
    launch_all<float>(d_in, (float*)d_ws, d_out, stream);
  else
    launch_all<__hip_bfloat16>(d_in, (__hip_bfloat16*)d_ws, d_out, stream);
}

// Round 8
// 395.505 us; speedup vs baseline: 1.1320x; 1.1320x over previous
//
#include <hip/hip_runtime.h>
#include <hip/hip_bf16.h>
#include <stdint.h>

#define L_ 25
#define E_ 64
#define H_ 8
#define B_ 1000
#define S_ 512
#define GQ 4                       // batch elements per block
#define NCELL (L_ * GQ)            // 100 cells per block
#define TPBR (NCELL * 8)           // 800 threads, thread = (cell, j)
#define TS 4                       // timesteps per superstep
#define NSUPER (S_ / TS + L_ - 1)  // 152 supersteps
#define HS 12                      // per-cell stride hrsh: 48B, banks disjoint
#define XG 36                      // per-cell stride xbuf: 144B (16B-aligned)

typedef float v2f __attribute__((ext_vector_type(2)));
typedef float v4f __attribute__((ext_vector_type(4)));

#define PIN(x) asm volatile("" : "+v"(x))

// v_pk_fma_f32: {a.x*b.x+c.x, a.y*b.y+c.y}
__device__ __forceinline__ v2f pkfma(v2f a, v2f b, v2f c) {
  v2f d;
  asm("v_pk_fma_f32 %0, %1, %2, %3" : "=v"(d) : "v"(a), "v"(b), "v"(c));
  return d;
}
// op_sel broadcast of a.x: {a.x*b.x+c.x, a.x*b.y+c.y}
__device__ __forceinline__ v2f pkfma_l(v2f a, v2f b, v2f c) {
  v2f d;
  asm("v_pk_fma_f32 %0, %1, %2, %3 op_sel:[0,0,0] op_sel_hi:[0,1,1]"
      : "=v"(d) : "v"(a), "v"(b), "v"(c));
  return d;
}
// op_sel broadcast of a.y: {a.y*b.x+c.x, a.y*b.y+c.y}
__device__ __forceinline__ v2f pkfma_h(v2f a, v2f b, v2f c) {
  v2f d;
  asm("v_pk_fma_f32 %0, %1, %2, %3 op_sel:[1,0,0] op_sel_hi:[1,1,1]"
      : "=v"(d) : "v"(a), "v"(b), "v"(c));
  return d;
}
__device__ __forceinline__ v2f pkadd(v2f a, v2f b) {
  v2f d;
  asm("v_pk_add_f32 %0, %1, %2" : "=v"(d) : "v"(a), "v"(b));
  return d;
}
__device__ __forceinline__ v2f vlo(v4f v) { return __builtin_shufflevector(v, v, 0, 1); }
__device__ __forceinline__ v2f vhi(v4f v) { return __builtin_shufflevector(v, v, 2, 3); }
__device__ __forceinline__ v2f mk2(float a, float b) { v2f r; r.x = a; r.y = b; return r; }

// zr chain over 8 k's: acc.{x=z,y=r} += sum_k m[k] * {Wz,Wr}[k]
#define CHAIN8(acc, ma, mb, w)            \
  acc = pkfma_l(vlo(ma), w[0], acc);      \
  acc = pkfma_h(vlo(ma), w[1], acc);      \
  acc = pkfma_l(vhi(ma), w[2], acc);      \
  acc = pkfma_h(vhi(ma), w[3], acc);      \
  acc = pkfma_l(vlo(mb), w[4], acc);      \
  acc = pkfma_h(vlo(mb), w[5], acc);      \
  acc = pkfma_l(vhi(mb), w[6], acc);      \
  acc = pkfma_h(vhi(mb), w[7], acc);

// element-wise paired chain: acc += {m[2q]*w[q].x, m[2q+1]*w[q].y}
#define CHAIN4P(acc, ma, mb, w)           \
  acc = pkfma(vlo(ma), w[0], acc);        \
  acc = pkfma(vhi(ma), w[1], acc);        \
  acc = pkfma(vlo(mb), w[2], acc);        \
  acc = pkfma(vhi(mb), w[3], acc);

__device__ __forceinline__ float ulo(uint32_t u) { return __uint_as_float(u << 16); }
__device__ __forceinline__ float uhi(uint32_t u) { return __uint_as_float(u & 0xffff0000u); }

__device__ __forceinline__ float toF(float v) { return v; }
__device__ __forceinline__ float toF(__hip_bfloat16 v) { return __bfloat162float(v); }
__device__ __forceinline__ void stP(float* p, float v) { *p = v; }
__device__ __forceinline__ void stP(__hip_bfloat16* p, float v) { *p = __float2bfloat16(v); }

__device__ __forceinline__ v2f loadC2(const float* p) { return *(const v2f*)p; }
__device__ __forceinline__ v2f loadC2(const __hip_bfloat16* p) {
  const uint32_t u = *(const uint32_t*)p;
  return mk2(ulo(u), uhi(u));
}

__device__ __forceinline__ void load8f(const __hip_bfloat16* p, float* o) {
  const uint4 v = *(const uint4*)p;
  o[0] = ulo(v.x); o[1] = uhi(v.x); o[2] = ulo(v.y); o[3] = uhi(v.y);
  o[4] = ulo(v.z); o[5] = uhi(v.z); o[6] = ulo(v.w); o[7] = uhi(v.w);
}
__device__ __forceinline__ void load8f(const float* p, float* o) {
  const float4 a = ((const float4*)p)[0];
  const float4 b = ((const float4*)p)[1];
  o[0] = a.x; o[1] = a.y; o[2] = a.z; o[3] = a.w;
  o[4] = b.x; o[5] = b.y; o[6] = b.z; o[7] = b.w;
}

__device__ __forceinline__ void st4(float* p, float a, float b, float c, float d) {
  float4 v; v.x = a; v.y = b; v.z = c; v.w = d;
  *(float4*)p = v;
}
__device__ __forceinline__ void st4(__hip_bfloat16* p, float a, float b, float c, float d) {
  __hip_bfloat16 t[4] = {__float2bfloat16(a), __float2bfloat16(b),
                         __float2bfloat16(c), __float2bfloat16(d)};
  *(ushort4*)p = *(ushort4*)t;
}

__device__ __forceinline__ float sigmo(float x) {
  return __builtin_amdgcn_rcpf(1.f + __expf(-x));
}

// Per-block dtype probe: max |bf16| of first 256 shorts of emb.
__device__ __forceinline__ void detect64(const unsigned short* __restrict__ u,
                                         int tid, float* fl) {
  if (tid < 64) {
    float m = 0.f;
#pragma unroll
    for (int k = 0; k < 4; ++k) {
      const uint32_t q = u[tid * 4 + k];
      float v = fabsf(__uint_as_float(q << 16));
      if (!(v < 1e30f)) v = 1e30f;
      m = fmaxf(m, v);
    }
#pragma unroll
    for (int off = 32; off; off >>= 1) m = fmaxf(m, __shfl_down(m, off, 64));
    if (tid == 0) *fl = (m > 2.0f) ? 0.f : 1.f;
  }
}

// ---------------------------------------------------------------------------
// Kernel 1: layer-0 x-projections. pre token layout (24 floats):
// [2j]={z_j}, [2j+1]={r_j}, [16+j]={h_j}.
// ---------------------------------------------------------------------------
template <typename T, typename PT>
__device__ __forceinline__ void pre_body(
    const int* __restrict__ x, const void* __restrict__ embv,
    const void* __restrict__ Wzv, const void* __restrict__ Wrv,
    const void* __restrict__ Whv, PT* __restrict__ pre,
    float* WL, float* TBb) {
  const T* emb = (const T*)embv;
  const T* Wz = (const T*)Wzv;
  const T* Wr = (const T*)Wrv;
  const T* Wh = (const T*)Whv;
  const int tid = threadIdx.x;

  for (int idx = tid; idx < 64 * 24; idx += 256) {
    const int k = idx / 24, c = idx - k * 24;
    float w;
    if (c < 16) w = toF(((c & 1) ? Wr : Wz)[k * 8 + (c >> 1)]);
    else        w = toF(Wh[k * 8 + (c - 16)]);
    WL[idx] = w;
  }
  __syncthreads();

  const int tok = blockIdx.x * 256 + tid;
  const int t = x[tok];

  v2f acc[12];
#pragma unroll
  for (int q = 0; q < 12; ++q) acc[q] = mk2(0.f, 0.f);

  for (int kb = 0; kb < 8; ++kb) {
    float e[8];
    load8f(emb + (size_t)t * E_ + kb * 8, e);
#pragma unroll
    for (int k8 = 0; k8 < 8; ++k8) {
      const v4f* wr = (const v4f*)(WL + (kb * 8 + k8) * 24);
      const v2f ee = mk2(e[k8], e[k8]);
#pragma unroll
      for (int q = 0; q < 6; ++q) {
        const v4f w4 = wr[q];
        acc[2 * q]     = pkfma(ee, vlo(w4), acc[2 * q]);
        acc[2 * q + 1] = pkfma(ee, vhi(w4), acc[2 * q + 1]);
      }
    }
  }

  // in-wave transpose: [24][65] per wave, conflict-free
  const int wid = tid >> 6, lane = tid & 63;
  float* tb = TBb + wid * (24 * 65);
#pragma unroll
  for (int q = 0; q < 12; ++q) {
    tb[(2 * q) * 65 + lane] = acc[q].x;
    tb[(2 * q + 1) * 65 + lane] = acc[q].y;
  }
  asm volatile("s_waitcnt lgkmcnt(0)" ::: "memory");
  __builtin_amdgcn_wave_barrier();

  PT* ob = pre + (size_t)(blockIdx.x * 256 + wid * 64) * 24;
#pragma unroll
  for (int it = 0; it < 6; ++it) {
    const int F0 = it * 256 + lane * 4;
    float o[4];
#pragma unroll
    for (int e2 = 0; e2 < 4; ++e2) {
      const int F = F0 + e2;
      const int tk = F / 24;
      const int c = F - tk * 24;
      o[e2] = tb[c * 65 + tk];
    }
    st4(ob + F0, o[0], o[1], o[2], o[3]);
  }
}

template <typename PT>
__global__ __launch_bounds__(256, 4) void gru_pre(
    const int* __restrict__ x, const void* __restrict__ emb,
    const void* __restrict__ Wz, const void* __restrict__ Wr,
    const void* __restrict__ Wh, PT* __restrict__ pre) {
  __shared__ __align__(16) float WL[64 * 24];
  __shared__ __align__(16) float TB[4][24 * 65];
  __shared__ float fl;
  detect64((const unsigned short*)emb, threadIdx.x, &fl);
  __syncthreads();
  if (fl != 0.f) pre_body<__hip_bfloat16, PT>(x, emb, Wz, Wr, Wh, pre, WL, &TB[0][0]);
  else           pre_body<float, PT>(x, emb, Wz, Wr, Wh, pre, WL, &TB[0][0]);
}

// ---------------------------------------------------------------------------
// Kernel 2: pipelined recurrence, TS=4, GQ=4, global __syncthreads.
// h-exchange unified into xbuf: the xc slot writes double as the intra-cell
// h exchange (T0 reads own opposite-parity slot 3; T1..T3 read slots 0..2 of
// the current parity). Independent x-chains and tile loads are placed INSIDE
// each timestep's ds round-trip windows (wave_barrier fences block the
// scheduler from doing this hoisting itself).
// ---------------------------------------------------------------------------
template <typename T, typename PT>
__device__ __forceinline__ void rec_body(
    const PT* __restrict__ pre,
    const void* __restrict__ Whz0v, const void* __restrict__ bz0v,
    const void* __restrict__ Whr0v, const void* __restrict__ br0v,
    const void* __restrict__ WrH0v, const void* __restrict__ bH0v,
    const void* __restrict__ Wxzv, const void* __restrict__ Whzv,
    const void* __restrict__ bzv, const void* __restrict__ Wxrv,
    const void* __restrict__ Whrv, const void* __restrict__ brv,
    const void* __restrict__ WxHv, const void* __restrict__ WrHv,
    const void* __restrict__ bHv, const void* __restrict__ Whyv,
    const void* __restrict__ byv, void* __restrict__ outv,
    float* hrsh, float* xbuf) {
  const T* Whz0 = (const T*)Whz0v; const T* bz0 = (const T*)bz0v;
  const T* Whr0 = (const T*)Whr0v; const T* br0 = (const T*)br0v;
  const T* WrH0 = (const T*)WrH0v; const T* bH0 = (const T*)bH0v;
  const T* Wxz = (const T*)Wxzv;   const T* Whz = (const T*)Whzv;
  const T* bz = (const T*)bzv;     const T* Wxr = (const T*)Wxrv;
  const T* Whr = (const T*)Whrv;   const T* br = (const T*)brv;
  const T* WxH = (const T*)WxHv;   const T* WrH = (const T*)WrHv;
  const T* bH = (const T*)bHv;     const T* Why = (const T*)Whyv;
  const T* by = (const T*)byv;     T* out = (T*)outv;

  const int tid = threadIdx.x;
  const int gi = tid >> 3;   // cell = l*GQ + g
  const int j = tid & 7;
  const int l = gi >> 2;     // GQ=4
  const int g = gi & 3;
  const int b = blockIdx.x * GQ + g;

  for (int i = tid; i < 2 * NCELL * XG; i += TPBR) xbuf[i] = 0.f;  // h0=0, l==0 x

  // ---- weights: z,r packed as {Wz[k][j], Wr[k][j]}; H-gate k-paired ----
  v2f wzrx[8], wzrh[8], wxh2[4], wrh2[4], bzr;
  float vbh;
  if (l == 0) {
#pragma unroll
    for (int k = 0; k < 8; ++k) {
      wzrh[k] = mk2(toF(Whz0[k * 8 + j]), toF(Whr0[k * 8 + j]));
      wzrx[k] = mk2(0.f, 0.f);
    }
#pragma unroll
    for (int q = 0; q < 4; ++q) {
      wrh2[q] = mk2(toF(WrH0[(2 * q) * 8 + j]), toF(WrH0[(2 * q + 1) * 8 + j]));
      wxh2[q] = mk2(0.f, 0.f);
    }
    bzr = mk2(toF(bz0[j]), toF(br0[j]));
    vbh = toF(bH0[j]);
  } else {
    const int base = (l - 1) * 64;
#pragma unroll
    for (int k = 0; k < 8; ++k) {
      wzrx[k] = mk2(toF(Wxz[base + k * 8 + j]), toF(Wxr[base + k * 8 + j]));
      wzrh[k] = mk2(toF(Whz[base + k * 8 + j]), toF(Whr[base + k * 8 + j]));
    }
#pragma unroll
    for (int q = 0; q < 4; ++q) {
      wxh2[q] = mk2(toF(WxH[base + (2 * q) * 8 + j]), toF(WxH[base + (2 * q + 1) * 8 + j]));
      wrh2[q] = mk2(toF(WrH[base + (2 * q) * 8 + j]), toF(WrH[base + (2 * q + 1) * 8 + j]));
    }
    bzr = mk2(toF(bz[(l - 1) * 8 + j]), toF(br[(l - 1) * 8 + j]));
    vbh = toF(bH[(l - 1) * 8 + j]);
  }
#pragma unroll
  for (int k = 0; k < 8; ++k) { PIN(wzrx[k]); PIN(wzrh[k]); }
#pragma unroll
  for (int q = 0; q < 4; ++q) { PIN(wxh2[q]); PIN(wrh2[q]); }
  PIN(bzr); PIN(vbh);

  // layer-0 precomputed x-projections for the 4 timesteps of this superstep
  const PT* ppr = pre + (size_t)b * (S_ * 24);
  v2f czr0 = mk2(0.f, 0.f), czr1 = czr0, czr2 = czr0, czr3 = czr0;
  float ch0 = 0.f, ch1 = 0.f, ch2 = 0.f, ch3 = 0.f;
  if (l == 0) {
    czr0 = loadC2(ppr + 0 * 24 + 2 * j);  ch0 = toF(ppr[0 * 24 + 16 + j]);
    czr1 = loadC2(ppr + 1 * 24 + 2 * j);  ch1 = toF(ppr[1 * 24 + 16 + j]);
    czr2 = loadC2(ppr + 2 * 24 + 2 * j);  ch2 = toF(ppr[2 * 24 + 16 + j]);
    czr3 = loadC2(ppr + 3 * 24 + 2 * j);  ch3 = toF(ppr[3 * 24 + 16 + j]);
  }

  float* hrg = hrsh + gi * HS;
  float* hrgj = hrg + j;
  const int gp = (gi >= GQ) ? (gi - GQ) * XG : 0;
  const float* xpe = xbuf + NCELL * XG + gp;  // consumer read when s even
  const float* xpo = xbuf + gp;               // consumer read when s odd
  float* xce = xbuf + gi * XG;                // own write when s even
  float* xco = xbuf + NCELL * XG + gi * XG;   // own write when s odd

  float hown = 0.f;

  __syncthreads();

  for (int s = 0; s < NSUPER; ++s) {
    const unsigned rel = (unsigned)(s - l);
    if (rel < (unsigned)(S_ / TS)) {
      const float* xp = (s & 1) ? xpo : xpe;
      float* xc = (s & 1) ? xco : xce;
      const float* xprev = (s & 1) ? xce : xco;  // own region of previous parity

      const v4f xa0 = ((const v4f*)xp)[0];
      const v4f xb0 = ((const v4f*)xp)[1];
      const v4f xa1 = ((const v4f*)xp)[2];
      const v4f xb1 = ((const v4f*)xp)[3];
      v4f xa2, xb2, xa3, xb3;
      v2f ax1, ah1v, ax2c, ah2v, ax3c, ah3v;
      float hn0, hn1, hn2, hn3;

      v2f nzr0 = mk2(0.f, 0.f), nzr1 = nzr0, nzr2 = nzr0, nzr3 = nzr0;
      float nh0 = 0.f, nh1 = 0.f, nh2 = 0.f, nh3 = 0.f;
      const bool pf = (l == 0) && (rel + 1u < (unsigned)(S_ / TS));

      // =================== T0 ===================
      {
        const v4f h01 = ((const v4f*)(xprev + 24))[0];  // own h of last superstep
        const v4f h23 = ((const v4f*)(xprev + 24))[1];
        // fill h-read latency: T0 + T1 x-chains (independent)
        v2f ax0 = czr0; CHAIN8(ax0, xa0, xb0, wzrx);
        v2f ah0v = mk2(ch0, vbh); CHAIN4P(ah0v, xa0, xb0, wxh2);
        ax1 = czr1; CHAIN8(ax1, xa1, xb1, wzrx);
        ah1v = mk2(ch1, vbh); CHAIN4P(ah1v, xa1, xb1, wxh2);
        v2f azrh = bzr; CHAIN8(azrh, h01, h23, wzrh);
        const v2f azr = pkadd(azrh, ax0);
        const float r_ = sigmo(azr.y);
        *hrgj = hown * r_;
        __builtin_amdgcn_wave_barrier();
        const v4f r01 = ((const v4f*)hrg)[0];
        const v4f r23 = ((const v4f*)hrg)[1];
        xa2 = ((const v4f*)xp)[4];  // issue T2 tile loads into the hr window
        xb2 = ((const v4f*)xp)[5];
        CHAIN4P(ah0v, r01, r23, wrh2);
        const float ah_ = ah0v.x + ah0v.y;
        const float ez_ = __expf(fminf(-azr.x, 30.f));
        const float eh_ = __expf(fminf(-2.f * ah_, 30.f));
        const float t_ = hown * ez_;
        const float nu_ = fmaf(eh_, t_ - 1.f, t_ + 1.f);
        const float de_ = (1.f + ez_) * (1.f + eh_);
        hn0 = nu_ * __builtin_amdgcn_rcpf(de_);
        xc[j] = hn0;
        __builtin_amdgcn_wave_barrier();
      }
      // =================== T1 ===================
      {
        const v4f h01 = ((const v4f*)xc)[0];   // slot 0 (= h after T0)
        const v4f h23 = ((const v4f*)xc)[1];
        xa3 = ((const v4f*)xp)[6];             // issue T3 tile loads
        xb3 = ((const v4f*)xp)[7];
        // fill h-read latency: T2 x-chains
        ax2c = czr2; CHAIN8(ax2c, xa2, xb2, wzrx);
        ah2v = mk2(ch2, vbh); CHAIN4P(ah2v, xa2, xb2, wxh2);
        v2f azrh = bzr; CHAIN8(azrh, h01, h23, wzrh);
        const v2f azr = pkadd(azrh, ax1);
        const float r_ = sigmo(azr.y);
        *hrgj = hn0 * r_;
        __builtin_amdgcn_wave_barrier();
        const v4f r01 = ((const v4f*)hrg)[0];
        const v4f r23 = ((const v4f*)hrg)[1];
        // fill hr-read latency: T3 x-chains
        ax3c = czr3; CHAIN8(ax3c, xa3, xb3, wzrx);
        ah3v = mk2(ch3, vbh); CHAIN4P(ah3v, xa3, xb3, wxh2);
        CHAIN4P(ah1v, r01, r23, wrh2);
        const float ah_ = ah1v.x + ah1v.y;
        const float ez_ = __expf(fminf(-azr.x, 30.f));
        const float eh_ = __expf(fminf(-2.f * ah_, 30.f));
        const float t_ = hn0 * ez_;
        const float nu_ = fmaf(eh_, t_ - 1.f, t_ + 1.f);
        const float de_ = (1.f + ez_) * (1.f + eh_);
        hn1 = nu_ * __builtin_amdgcn_rcpf(de_);
        xc[8 + j] = hn1;
        __builtin_amdgcn_wave_barrier();
      }
      // =================== T2 ===================
      {
        const v4f h01 = ((const v4f*)(xc + 8))[0];  // slot 1
        const v4f h23 = ((const v4f*)(xc + 8))[1];
        // fill h-read latency: l==0 global prefetch (vmcnt, overlaps freely)
        if (pf) {
          const PT* pn = ppr + (TS * rel + 4) * 24;
          nzr0 = loadC2(pn + 0 * 24 + 2 * j);  nh0 = toF(pn[0 * 24 + 16 + j]);
          nzr1 = loadC2(pn + 1 * 24 + 2 * j);  nh1 = toF(pn[1 * 24 + 16 + j]);
          nzr2 = loadC2(pn + 2 * 24 + 2 * j);  nh2 = toF(pn[2 * 24 + 16 + j]);
          nzr3 = loadC2(pn + 3 * 24 + 2 * j);  nh3 = toF(pn[3 * 24 + 16 + j]);
        }
        v2f azrh = bzr; CHAIN8(azrh, h01, h23, wzrh);
        const v2f azr = pkadd(azrh, ax2c);
        const float r_ = sigmo(azr.y);
        *hrgj = hn1 * r_;
        __builtin_amdgcn_wave_barrier();
        const v4f r01 = ((const v4f*)hrg)[0];
        const v4f r23 = ((const v4f*)hrg)[1];
        CHAIN4P(ah2v, r01, r23, wrh2);
        const float ah_ = ah2v.x + ah2v.y;
        const float ez_ = __expf(fminf(-azr.x, 30.f));
        const float eh_ = __expf(fminf(-2.f * ah_, 30.f));
        const float t_ = hn1 * ez_;
        const float nu_ = fmaf(eh_, t_ - 1.f, t_ + 1.f);
        const float de_ = (1.f + ez_) * (1.f + eh_);
        hn2 = nu_ * __builtin_amdgcn_rcpf(de_);
        xc[16 + j] = hn2;
        __builtin_amdgcn_wave_barrier();
      }
      // =================== T3 ===================
      {
        const v4f h01 = ((const v4f*)(xc + 16))[0];  // slot 2
        const v4f h23 = ((const v4f*)(xc + 16))[1];
        v2f azrh = bzr; CHAIN8(azrh, h01, h23, wzrh);
        const v2f azr = pkadd(azrh, ax3c);
        const float r_ = sigmo(azr.y);
        *hrgj = hn2 * r_;
        __builtin_amdgcn_wave_barrier();
        const v4f r01 = ((const v4f*)hrg)[0];
        const v4f r23 = ((const v4f*)hrg)[1];
        CHAIN4P(ah3v, r01, r23, wrh2);
        const float ah_ = ah3v.x + ah3v.y;
        const float ez_ = __expf(fminf(-azr.x, 30.f));
        const float eh_ = __expf(fminf(-2.f * ah_, 30.f));
        const float t_ = hn2 * ez_;
        const float nu_ = fmaf(eh_, t_ - 1.f, t_ + 1.f);
        const float de_ = (1.f + ez_) * (1.f + eh_);
        hn3 = nu_ * __builtin_amdgcn_rcpf(de_);
        xc[24 + j] = hn3;
        __builtin_amdgcn_wave_barrier();
      }

      hown = hn3;
      czr0 = nzr0; ch0 = nh0; czr1 = nzr1; ch1 = nh1;
      czr2 = nzr2; ch2 = nh2; czr3 = nzr3; ch3 = nh3;
    }
    __syncthreads();
  }

  // ---- epilogue ----
  stP(out + B_ + (l * B_ + b) * H_ + j, hown);
  if (l == L_ - 1 && j == 0) {
    // final superstep for layer L-1 is s=151 (odd) -> writes went to xco slot 3
    const float* hf = xbuf + NCELL * XG + gi * XG + 24;
    float ssum = toF(by[0]);
#pragma unroll
    for (int k = 0; k < 8; ++k) ssum = fmaf(hf[k], toF(Why[k]), ssum);
    stP(out + b, ssum);
  }
}

template <typename PT>
__global__ __launch_bounds__(TPBR, 4) void gru_rec(
    const void* __restrict__ emb, const PT* __restrict__ pre,
    const void* __restrict__ Whz0, const void* __restrict__ bz0,
    const void* __restrict__ Whr0, const void* __restrict__ br0,
    const void* __restrict__ WrH0, const void* __restrict__ bH0,
    const void* __restrict__ Wxz, const void* __restrict__ Whz,
    const void* __restrict__ bz, const void* __restrict__ Wxr,
    const void* __restrict__ Whr, const void* __restrict__ br,
    const void* __restrict__ WxH, const void* __restrict__ WrH,
    const void* __restrict__ bH, const void* __restrict__ Why,
    const void* __restrict__ by, void* __restrict__ out) {
  __shared__ __align__(16) float hrsh[NCELL * HS];
  __shared__ __align__(16) float xbuf[2 * NCELL * XG];
  __shared__ float fl;
  detect64((const unsigned short*)emb, threadIdx.x, &fl);
  __syncthreads();
  if (fl != 0.f)
    rec_body<__hip_bfloat16, PT>(pre, Whz0, bz0, Whr0, br0, WrH0, bH0, Wxz, Whz,
                                 bz, Wxr, Whr, br, WxH, WrH, bH, Why, by, out,
                                 hrsh, xbuf);
  else
    rec_body<float, PT>(pre, Whz0, bz0, Whr0, br0, WrH0, bH0, Wxz, Whz, bz, Wxr,
                        Whr, br, WxH, WrH, bH, Why, by, out, hrsh, xbuf);
}

// ---------------------------------------------------------------------------
template <typename PT>
static void launch_all(void* const* d_in, PT* pre, void* d_out, hipStream_t stream) {
  gru_pre<PT><<<B_ * S_ / 256, 256, 0, stream>>>(
      (const int*)d_in[0], d_in[1], d_in[2], d_in[5], d_in[8], pre);
  gru_rec<PT><<<B_ / GQ, TPBR, 0, stream>>>(
      d_in[1], pre, d_in[3], d_in[4], d_in[6], d_in[7], d_in[9], d_in[10],
      d_in[11], d_in[12], d_in[13], d_in[14], d_in[15], d_in[16], d_in[17],
      d_in[18], d_in[19], d_in[20], d_in[21], d_out);
}

extern "C" void kernel_launch(void* const* d_in, const int* in_sizes, int n_in,
                              void* d_out, int out_size, void* d_ws, size_t ws_size,
                              hipStream_t stream) {
  const size_t needF = (size_t)B_ * S_ * 24 * sizeof(float);
  if (ws_size >= needF)
    launch_all<float>(d_in, (float*)d_ws, d_out, stream);
  else
    launch_all<__hip_bfloat16>(d_in, (__hip_bfloat16*)d_ws, d_out, stream);
}

// Round 9
// 389.318 us; speedup vs baseline: 1.1500x; 1.0159x over previous
//
#include <hip/hip_runtime.h>
#include <hip/hip_bf16.h>
#include <stdint.h>

#define L_ 25
#define E_ 64
#define H_ 8
#define B_ 1000
#define S_ 512
#define GQ 4                       // batch elements per block
#define NCELL (L_ * GQ)            // 100 cells per block
#define TPBR (NCELL * 8)           // 800 threads, thread = (cell, j)
#define TS 4                       // timesteps per superstep
#define NSUPER (S_ / TS + L_ - 1)  // 152 supersteps
#define NW ((TPBR + 63) / 64)      // 13 waves (last is half)
#define HS 12                      // per-cell stride hrsh: 48B, banks disjoint
#define XG 36                      // per-cell stride xbuf: 144B (16B-aligned)

typedef float v2f __attribute__((ext_vector_type(2)));
typedef float v4f __attribute__((ext_vector_type(4)));

#define PIN(x) asm volatile("" : "+v"(x))
#define LGKM0() asm volatile("s_waitcnt lgkmcnt(0)" ::: "memory")

// v_pk_fma_f32: {a.x*b.x+c.x, a.y*b.y+c.y}
__device__ __forceinline__ v2f pkfma(v2f a, v2f b, v2f c) {
  v2f d;
  asm("v_pk_fma_f32 %0, %1, %2, %3" : "=v"(d) : "v"(a), "v"(b), "v"(c));
  return d;
}
// op_sel broadcast of a.x: {a.x*b.x+c.x, a.x*b.y+c.y}
__device__ __forceinline__ v2f pkfma_l(v2f a, v2f b, v2f c) {
  v2f d;
  asm("v_pk_fma_f32 %0, %1, %2, %3 op_sel:[0,0,0] op_sel_hi:[0,1,1]"
      : "=v"(d) : "v"(a), "v"(b), "v"(c));
  return d;
}
// op_sel broadcast of a.y: {a.y*b.x+c.x, a.y*b.y+c.y}
__device__ __forceinline__ v2f pkfma_h(v2f a, v2f b, v2f c) {
  v2f d;
  asm("v_pk_fma_f32 %0, %1, %2, %3 op_sel:[1,0,0] op_sel_hi:[1,1,1]"
      : "=v"(d) : "v"(a), "v"(b), "v"(c));
  return d;
}
__device__ __forceinline__ v2f pkadd(v2f a, v2f b) {
  v2f d;
  asm("v_pk_add_f32 %0, %1, %2" : "=v"(d) : "v"(a), "v"(b));
  return d;
}
__device__ __forceinline__ v2f vlo(v4f v) { return __builtin_shufflevector(v, v, 0, 1); }
__device__ __forceinline__ v2f vhi(v4f v) { return __builtin_shufflevector(v, v, 2, 3); }
__device__ __forceinline__ v2f mk2(float a, float b) { v2f r; r.x = a; r.y = b; return r; }

// zr chain over 8 k's: acc.{x=z,y=r} += sum_k m[k] * {Wz,Wr}[k]
#define CHAIN8(acc, ma, mb, w)            \
  acc = pkfma_l(vlo(ma), w[0], acc);      \
  acc = pkfma_h(vlo(ma), w[1], acc);      \
  acc = pkfma_l(vhi(ma), w[2], acc);      \
  acc = pkfma_h(vhi(ma), w[3], acc);      \
  acc = pkfma_l(vlo(mb), w[4], acc);      \
  acc = pkfma_h(vlo(mb), w[5], acc);      \
  acc = pkfma_l(vhi(mb), w[6], acc);      \
  acc = pkfma_h(vhi(mb), w[7], acc);

// element-wise paired chain: acc += {m[2q]*w[q].x, m[2q+1]*w[q].y}
#define CHAIN4P(acc, ma, mb, w)           \
  acc = pkfma(vlo(ma), w[0], acc);        \
  acc = pkfma(vhi(ma), w[1], acc);        \
  acc = pkfma(vlo(mb), w[2], acc);        \
  acc = pkfma(vhi(mb), w[3], acc);

__device__ __forceinline__ float ulo(uint32_t u) { return __uint_as_float(u << 16); }
__device__ __forceinline__ float uhi(uint32_t u) { return __uint_as_float(u & 0xffff0000u); }

__device__ __forceinline__ float toF(float v) { return v; }
__device__ __forceinline__ float toF(__hip_bfloat16 v) { return __bfloat162float(v); }
__device__ __forceinline__ void stP(float* p, float v) { *p = v; }
__device__ __forceinline__ void stP(__hip_bfloat16* p, float v) { *p = __float2bfloat16(v); }

__device__ __forceinline__ v2f loadC2(const float* p) { return *(const v2f*)p; }
__device__ __forceinline__ v2f loadC2(const __hip_bfloat16* p) {
  const uint32_t u = *(const uint32_t*)p;
  return mk2(ulo(u), uhi(u));
}

__device__ __forceinline__ void load8f(const __hip_bfloat16* p, float* o) {
  const uint4 v = *(const uint4*)p;
  o[0] = ulo(v.x); o[1] = uhi(v.x); o[2] = ulo(v.y); o[3] = uhi(v.y);
  o[4] = ulo(v.z); o[5] = uhi(v.z); o[6] = ulo(v.w); o[7] = uhi(v.w);
}
__device__ __forceinline__ void load8f(const float* p, float* o) {
  const float4 a = ((const float4*)p)[0];
  const float4 b = ((const float4*)p)[1];
  o[0] = a.x; o[1] = a.y; o[2] = a.z; o[3] = a.w;
  o[4] = b.x; o[5] = b.y; o[6] = b.z; o[7] = b.w;
}

__device__ __forceinline__ void st4(float* p, float a, float b, float c, float d) {
  float4 v; v.x = a; v.y = b; v.z = c; v.w = d;
  *(float4*)p = v;
}
__device__ __forceinline__ void st4(__hip_bfloat16* p, float a, float b, float c, float d) {
  __hip_bfloat16 t[4] = {__float2bfloat16(a), __float2bfloat16(b),
                         __float2bfloat16(c), __float2bfloat16(d)};
  *(ushort4*)p = *(ushort4*)t;
}

__device__ __forceinline__ float sigmo(float x) {
  return __builtin_amdgcn_rcpf(1.f + __expf(-x));
}

// ---- LDS flag protocol (proven min-progress-live; hardened w/ atomics) ----
__device__ __forceinline__ void wait_ge(int* p, int s) {
  while (__hip_atomic_load(p, __ATOMIC_ACQUIRE, __HIP_MEMORY_SCOPE_WORKGROUP) < s)
    __builtin_amdgcn_s_sleep(2);
}
__device__ __forceinline__ void sig(int* p, int v) {
  __hip_atomic_store(p, v, __ATOMIC_RELEASE, __HIP_MEMORY_SCOPE_WORKGROUP);
}

// Per-block dtype probe: max |bf16| of first 256 shorts of emb.
__device__ __forceinline__ void detect64(const unsigned short* __restrict__ u,
                                         int tid, float* fl) {
  if (tid < 64) {
    float m = 0.f;
#pragma unroll
    for (int k = 0; k < 4; ++k) {
      const uint32_t q = u[tid * 4 + k];
      float v = fabsf(__uint_as_float(q << 16));
      if (!(v < 1e30f)) v = 1e30f;
      m = fmaxf(m, v);
    }
#pragma unroll
    for (int off = 32; off; off >>= 1) m = fmaxf(m, __shfl_down(m, off, 64));
    if (tid == 0) *fl = (m > 2.0f) ? 0.f : 1.f;
  }
}

// ---------------------------------------------------------------------------
// Kernel 1: layer-0 x-projections. pre token layout (24 floats):
// [2j]={z_j}, [2j+1]={r_j}, [16+j]={h_j}.
// ---------------------------------------------------------------------------
template <typename T, typename PT>
__device__ __forceinline__ void pre_body(
    const int* __restrict__ x, const void* __restrict__ embv,
    const void* __restrict__ Wzv, const void* __restrict__ Wrv,
    const void* __restrict__ Whv, PT* __restrict__ pre,
    float* WL, float* TBb) {
  const T* emb = (const T*)embv;
  const T* Wz = (const T*)Wzv;
  const T* Wr = (const T*)Wrv;
  const T* Wh = (const T*)Whv;
  const int tid = threadIdx.x;

  for (int idx = tid; idx < 64 * 24; idx += 256) {
    const int k = idx / 24, c = idx - k * 24;
    float w;
    if (c < 16) w = toF(((c & 1) ? Wr : Wz)[k * 8 + (c >> 1)]);
    else        w = toF(Wh[k * 8 + (c - 16)]);
    WL[idx] = w;
  }
  __syncthreads();

  const int tok = blockIdx.x * 256 + tid;
  const int t = x[tok];

  v2f acc[12];
#pragma unroll
  for (int q = 0; q < 12; ++q) acc[q] = mk2(0.f, 0.f);

  for (int kb = 0; kb < 8; ++kb) {
    float e[8];
    load8f(emb + (size_t)t * E_ + kb * 8, e);
#pragma unroll
    for (int k8 = 0; k8 < 8; ++k8) {
      const v4f* wr = (const v4f*)(WL + (kb * 8 + k8) * 24);
      const v2f ee = mk2(e[k8], e[k8]);
#pragma unroll
      for (int q = 0; q < 6; ++q) {
        const v4f w4 = wr[q];
        acc[2 * q]     = pkfma(ee, vlo(w4), acc[2 * q]);
        acc[2 * q + 1] = pkfma(ee, vhi(w4), acc[2 * q + 1]);
      }
    }
  }

  // in-wave transpose: [24][65] per wave, conflict-free
  const int wid = tid >> 6, lane = tid & 63;
  float* tb = TBb + wid * (24 * 65);
#pragma unroll
  for (int q = 0; q < 12; ++q) {
    tb[(2 * q) * 65 + lane] = acc[q].x;
    tb[(2 * q + 1) * 65 + lane] = acc[q].y;
  }
  LGKM0();
  __builtin_amdgcn_wave_barrier();

  PT* ob = pre + (size_t)(blockIdx.x * 256 + wid * 64) * 24;
#pragma unroll
  for (int it = 0; it < 6; ++it) {
    const int F0 = it * 256 + lane * 4;
    float o[4];
#pragma unroll
    for (int e2 = 0; e2 < 4; ++e2) {
      const int F = F0 + e2;
      const int tk = F / 24;
      const int c = F - tk * 24;
      o[e2] = tb[c * 65 + tk];
    }
    st4(ob + F0, o[0], o[1], o[2], o[3]);
  }
}

template <typename PT>
__global__ __launch_bounds__(256, 4) void gru_pre(
    const int* __restrict__ x, const void* __restrict__ emb,
    const void* __restrict__ Wz, const void* __restrict__ Wr,
    const void* __restrict__ Wh, PT* __restrict__ pre) {
  __shared__ __align__(16) float WL[64 * 24];
  __shared__ __align__(16) float TB[4][24 * 65];
  __shared__ float fl;
  detect64((const unsigned short*)emb, threadIdx.x, &fl);
  __syncthreads();
  if (fl != 0.f) pre_body<__hip_bfloat16, PT>(x, emb, Wz, Wr, Wh, pre, WL, &TB[0][0]);
  else           pre_body<float, PT>(x, emb, Wz, Wr, Wh, pre, WL, &TB[0][0]);
}

// ---------------------------------------------------------------------------
// Kernel 2: pipelined recurrence, TS=4, GQ=4, NO per-superstep __syncthreads.
// Wave-chain flag sync: prog[w] = supersteps wave w completed (all xc writes
// drained); cons[w] = supersteps whose producer buffer wave w finished
// reading. Wave w at superstep s waits prog[w-1] >= s and cons[w+1] >= s.
// Flag value = completed count; wave at the global min superstep always
// passes both guards -> deadlock-free. h-exchange unified in xbuf (R8).
// ---------------------------------------------------------------------------
template <typename T, typename PT>
__device__ __forceinline__ void rec_body(
    const PT* __restrict__ pre,
    const void* __restrict__ Whz0v, const void* __restrict__ bz0v,
    const void* __restrict__ Whr0v, const void* __restrict__ br0v,
    const void* __restrict__ WrH0v, const void* __restrict__ bH0v,
    const void* __restrict__ Wxzv, const void* __restrict__ Whzv,
    const void* __restrict__ bzv, const void* __restrict__ Wxrv,
    const void* __restrict__ Whrv, const void* __restrict__ brv,
    const void* __restrict__ WxHv, const void* __restrict__ WrHv,
    const void* __restrict__ bHv, const void* __restrict__ Whyv,
    const void* __restrict__ byv, void* __restrict__ outv,
    float* hrsh, float* xbuf, int* sflags) {
  const T* Whz0 = (const T*)Whz0v; const T* bz0 = (const T*)bz0v;
  const T* Whr0 = (const T*)Whr0v; const T* br0 = (const T*)br0v;
  const T* WrH0 = (const T*)WrH0v; const T* bH0 = (const T*)bH0v;
  const T* Wxz = (const T*)Wxzv;   const T* Whz = (const T*)Whzv;
  const T* bz = (const T*)bzv;     const T* Wxr = (const T*)Wxrv;
  const T* Whr = (const T*)Whrv;   const T* br = (const T*)brv;
  const T* WxH = (const T*)WxHv;   const T* WrH = (const T*)WrHv;
  const T* bH = (const T*)bHv;     const T* Why = (const T*)Whyv;
  const T* by = (const T*)byv;     T* out = (T*)outv;

  const int tid = threadIdx.x;
  const int gi = tid >> 3;   // cell = l*GQ + g
  const int j = tid & 7;
  const int l = gi >> 2;     // GQ=4
  const int g = gi & 3;
  const int b = blockIdx.x * GQ + g;
  const int w = tid >> 6;    // wave id 0..12 (wave 12 is half)
  const bool lane0 = (tid & 63) == 0;

  for (int i = tid; i < 2 * NCELL * XG; i += TPBR) xbuf[i] = 0.f;  // h0=0, l==0 x
  for (int i = tid; i < 32; i += TPBR) sflags[i] = 0;

  // ---- weights: z,r packed as {Wz[k][j], Wr[k][j]}; H-gate k-paired ----
  v2f wzrx[8], wzrh[8], wxh2[4], wrh2[4], bzr;
  float vbh;
  if (l == 0) {
#pragma unroll
    for (int k = 0; k < 8; ++k) {
      wzrh[k] = mk2(toF(Whz0[k * 8 + j]), toF(Whr0[k * 8 + j]));
      wzrx[k] = mk2(0.f, 0.f);
    }
#pragma unroll
    for (int q = 0; q < 4; ++q) {
      wrh2[q] = mk2(toF(WrH0[(2 * q) * 8 + j]), toF(WrH0[(2 * q + 1) * 8 + j]));
      wxh2[q] = mk2(0.f, 0.f);
    }
    bzr = mk2(toF(bz0[j]), toF(br0[j]));
    vbh = toF(bH0[j]);
  } else {
    const int base = (l - 1) * 64;
#pragma unroll
    for (int k = 0; k < 8; ++k) {
      wzrx[k] = mk2(toF(Wxz[base + k * 8 + j]), toF(Wxr[base + k * 8 + j]));
      wzrh[k] = mk2(toF(Whz[base + k * 8 + j]), toF(Whr[base + k * 8 + j]));
    }
#pragma unroll
    for (int q = 0; q < 4; ++q) {
      wxh2[q] = mk2(toF(WxH[base + (2 * q) * 8 + j]), toF(WxH[base + (2 * q + 1) * 8 + j]));
      wrh2[q] = mk2(toF(WrH[base + (2 * q) * 8 + j]), toF(WrH[base + (2 * q + 1) * 8 + j]));
    }
    bzr = mk2(toF(bz[(l - 1) * 8 + j]), toF(br[(l - 1) * 8 + j]));
    vbh = toF(bH[(l - 1) * 8 + j]);
  }
#pragma unroll
  for (int k = 0; k < 8; ++k) { PIN(wzrx[k]); PIN(wzrh[k]); }
#pragma unroll
  for (int q = 0; q < 4; ++q) { PIN(wxh2[q]); PIN(wrh2[q]); }
  PIN(bzr); PIN(vbh);

  // layer-0 precomputed x-projections for the 4 timesteps of this superstep
  const PT* ppr = pre + (size_t)b * (S_ * 24);
  v2f czr0 = mk2(0.f, 0.f), czr1 = czr0, czr2 = czr0, czr3 = czr0;
  float ch0 = 0.f, ch1 = 0.f, ch2 = 0.f, ch3 = 0.f;
  if (l == 0) {
    czr0 = loadC2(ppr + 0 * 24 + 2 * j);  ch0 = toF(ppr[0 * 24 + 16 + j]);
    czr1 = loadC2(ppr + 1 * 24 + 2 * j);  ch1 = toF(ppr[1 * 24 + 16 + j]);
    czr2 = loadC2(ppr + 2 * 24 + 2 * j);  ch2 = toF(ppr[2 * 24 + 16 + j]);
    czr3 = loadC2(ppr + 3 * 24 + 2 * j);  ch3 = toF(ppr[3 * 24 + 16 + j]);
  }

  float* hrg = hrsh + gi * HS;
  float* hrgj = hrg + j;
  const int gp = (gi >= GQ) ? (gi - GQ) * XG : 0;
  const float* xpe = xbuf + NCELL * XG + gp;  // consumer read when s even
  const float* xpo = xbuf + gp;               // consumer read when s odd
  float* xce = xbuf + gi * XG;                // own write when s even
  float* xco = xbuf + NCELL * XG + gi * XG;   // own write when s odd

  float hown = 0.f;

  __syncthreads();  // once: zero-init + flags visible to all waves

  for (int s = 0; s < NSUPER; ++s) {
    // ---- pairwise chain sync ----
    if (w > 0)      wait_ge(sflags + (w - 1), s);       // producer data ready
    if (w < NW - 1) wait_ge(sflags + 16 + (w + 1), s);  // consumer freed buffer
    asm volatile("" ::: "memory");

    const unsigned rel = (unsigned)(s - l);
    if (rel < (unsigned)(S_ / TS)) {
      const float* xp = (s & 1) ? xpo : xpe;
      float* xc = (s & 1) ? xco : xce;
      const float* xprev = (s & 1) ? xce : xco;  // own region of previous parity

      const v4f xa0 = ((const v4f*)xp)[0];
      const v4f xb0 = ((const v4f*)xp)[1];
      const v4f xa1 = ((const v4f*)xp)[2];
      const v4f xb1 = ((const v4f*)xp)[3];
      v4f xa2, xb2, xa3, xb3;
      v2f ax1, ah1v, ax2c, ah2v, ax3c, ah3v;
      float hn0, hn1, hn2, hn3;

      v2f nzr0 = mk2(0.f, 0.f), nzr1 = nzr0, nzr2 = nzr0, nzr3 = nzr0;
      float nh0 = 0.f, nh1 = 0.f, nh2 = 0.f, nh3 = 0.f;
      const bool pf = (l == 0) && (rel + 1u < (unsigned)(S_ / TS));

      // =================== T0 ===================
      {
        const v4f h01 = ((const v4f*)(xprev + 24))[0];  // own h of last superstep
        const v4f h23 = ((const v4f*)(xprev + 24))[1];
        // fill h-read latency: T0 + T1 x-chains (independent)
        v2f ax0 = czr0; CHAIN8(ax0, xa0, xb0, wzrx);
        v2f ah0v = mk2(ch0, vbh); CHAIN4P(ah0v, xa0, xb0, wxh2);
        ax1 = czr1; CHAIN8(ax1, xa1, xb1, wzrx);
        ah1v = mk2(ch1, vbh); CHAIN4P(ah1v, xa1, xb1, wxh2);
        v2f azrh = bzr; CHAIN8(azrh, h01, h23, wzrh);
        const v2f azr = pkadd(azrh, ax0);
        const float r_ = sigmo(azr.y);
        *hrgj = hown * r_;
        __builtin_amdgcn_wave_barrier();
        const v4f r01 = ((const v4f*)hrg)[0];
        const v4f r23 = ((const v4f*)hrg)[1];
        xa2 = ((const v4f*)xp)[4];  // issue T2 tile loads into the hr window
        xb2 = ((const v4f*)xp)[5];
        CHAIN4P(ah0v, r01, r23, wrh2);
        const float ah_ = ah0v.x + ah0v.y;
        const float ez_ = __expf(fminf(-azr.x, 30.f));
        const float eh_ = __expf(fminf(-2.f * ah_, 30.f));
        const float t_ = hown * ez_;
        const float nu_ = fmaf(eh_, t_ - 1.f, t_ + 1.f);
        const float de_ = (1.f + ez_) * (1.f + eh_);
        hn0 = nu_ * __builtin_amdgcn_rcpf(de_);
        xc[j] = hn0;
        __builtin_amdgcn_wave_barrier();
      }
      // =================== T1 ===================
      {
        const v4f h01 = ((const v4f*)xc)[0];   // slot 0 (= h after T0)
        const v4f h23 = ((const v4f*)xc)[1];
        xa3 = ((const v4f*)xp)[6];             // last reads of producer buffer
        xb3 = ((const v4f*)xp)[7];
        LGKM0();                               // all xp reads retired
        if (lane0) sig(sflags + 16 + w, s + 1);  // signal: buffer consumed
        // fill h-read latency: T2 x-chains
        ax2c = czr2; CHAIN8(ax2c, xa2, xb2, wzrx);
        ah2v = mk2(ch2, vbh); CHAIN4P(ah2v, xa2, xb2, wxh2);
        v2f azrh = bzr; CHAIN8(azrh, h01, h23, wzrh);
        const v2f azr = pkadd(azrh, ax1);
        const float r_ = sigmo(azr.y);
        *hrgj = hn0 * r_;
        __builtin_amdgcn_wave_barrier();
        const v4f r01 = ((const v4f*)hrg)[0];
        const v4f r23 = ((const v4f*)hrg)[1];
        // fill hr-read latency: T3 x-chains
        ax3c = czr3; CHAIN8(ax3c, xa3, xb3, wzrx);
        ah3v = mk2(ch3, vbh); CHAIN4P(ah3v, xa3, xb3, wxh2);
        CHAIN4P(ah1v, r01, r23, wrh2);
        const float ah_ = ah1v.x + ah1v.y;
        const float ez_ = __expf(fminf(-azr.x, 30.f));
        const float eh_ = __expf(fminf(-2.f * ah_, 30.f));
        const float t_ = hn0 * ez_;
        const float nu_ = fmaf(eh_, t_ - 1.f, t_ + 1.f);
        const float de_ = (1.f + ez_) * (1.f + eh_);
        hn1 = nu_ * __builtin_amdgcn_rcpf(de_);
        xc[8 + j] = hn1;
        __builtin_amdgcn_wave_barrier();
      }
      // =================== T2 ===================
      {
        const v4f h01 = ((const v4f*)(xc + 8))[0];  // slot 1
        const v4f h23 = ((const v4f*)(xc + 8))[1];
        // fill h-read latency: l==0 global prefetch (vmcnt, overlaps freely)
        if (pf) {
          const PT* pn = ppr + (TS * rel + 4) * 24;
          nzr0 = loadC2(pn + 0 * 24 + 2 * j);  nh0 = toF(pn[0 * 24 + 16 + j]);
          nzr1 = loadC2(pn + 1 * 24 + 2 * j);  nh1 = toF(pn[1 * 24 + 16 + j]);
          nzr2 = loadC2(pn + 2 * 24 + 2 * j);  nh2 = toF(pn[2 * 24 + 16 + j]);
          nzr3 = loadC2(pn + 3 * 24 + 2 * j);  nh3 = toF(pn[3 * 24 + 16 + j]);
        }
        v2f azrh = bzr; CHAIN8(azrh, h01, h23, wzrh);
        const v2f azr = pkadd(azrh, ax2c);
        const float r_ = sigmo(azr.y);
        *hrgj = hn1 * r_;
        __builtin_amdgcn_wave_barrier();
        const v4f r01 = ((const v4f*)hrg)[0];
        const v4f r23 = ((const v4f*)hrg)[1];
        CHAIN4P(ah2v, r01, r23, wrh2);
        const float ah_ = ah2v.x + ah2v.y;
        const float ez_ = __expf(fminf(-azr.x, 30.f));
        const float eh_ = __expf(fminf(-2.f * ah_, 30.f));
        const float t_ = hn1 * ez_;
        const float nu_ = fmaf(eh_, t_ - 1.f, t_ + 1.f);
        const float de_ = (1.f + ez_) * (1.f + eh_);
        hn2 = nu_ * __builtin_amdgcn_rcpf(de_);
        xc[16 + j] = hn2;
        __builtin_amdgcn_wave_barrier();
      }
      // =================== T3 ===================
      {
        const v4f h01 = ((const v4f*)(xc + 16))[0];  // slot 2
        const v4f h23 = ((const v4f*)(xc + 16))[1];
        v2f azrh = bzr; CHAIN8(azrh, h01, h23, wzrh);
        const v2f azr = pkadd(azrh, ax3c);
        const float r_ = sigmo(azr.y);
        *hrgj = hn2 * r_;
        __builtin_amdgcn_wave_barrier();
        const v4f r01 = ((const v4f*)hrg)[0];
        const v4f r23 = ((const v4f*)hrg)[1];
        CHAIN4P(ah3v, r01, r23, wrh2);
        const float ah_ = ah3v.x + ah3v.y;
        const float ez_ = __expf(fminf(-azr.x, 30.f));
        const float eh_ = __expf(fminf(-2.f * ah_, 30.f));
        const float t_ = hn2 * ez_;
        const float nu_ = fmaf(eh_, t_ - 1.f, t_ + 1.f);
        const float de_ = (1.f + ez_) * (1.f + eh_);
        hn3 = nu_ * __builtin_amdgcn_rcpf(de_);
        xc[24 + j] = hn3;
        __builtin_amdgcn_wave_barrier();
      }

      hown = hn3;
      czr0 = nzr0; ch0 = nh0; czr1 = nzr1; ch1 = nh1;
      czr2 = nzr2; ch2 = nh2; czr3 = nzr3; ch3 = nh3;

      LGKM0();                          // xc writes landed
      if (lane0) sig(sflags + w, s + 1);  // signal: superstep written
    } else {
      // inactive superstep: nothing read/written, advance both flags
      if (lane0) { sig(sflags + 16 + w, s + 1); sig(sflags + w, s + 1); }
    }
  }

  // ---- epilogue (waves finish independently; own data only) ----
  stP(out + B_ + (l * B_ + b) * H_ + j, hown);
  if (l == L_ - 1 && j == 0) {
    // final superstep for layer L-1 is s=151 (odd) -> writes went to xco slot 3
    const float* hf = xbuf + NCELL * XG + gi * XG + 24;
    float ssum = toF(by[0]);
#pragma unroll
    for (int k = 0; k < 8; ++k) ssum = fmaf(hf[k], toF(Why[k]), ssum);
    stP(out + b, ssum);
  }
}

template <typename PT>
__global__ __launch_bounds__(TPBR, 4) void gru_rec(
    const void* __restrict__ emb, const PT* __restrict__ pre,
    const void* __restrict__ Whz0, const void* __restrict__ bz0,
    const void* __restrict__ Whr0, const void* __restrict__ br0,
    const void* __restrict__ WrH0, const void* __restrict__ bH0,
    const void* __restrict__ Wxz, const void* __restrict__ Whz,
    const void* __restrict__ bz, const void* __restrict__ Wxr,
    const void* __restrict__ Whr, const void* __restrict__ br,
    const void* __restrict__ WxH, const void* __restrict__ WrH,
    const void* __restrict__ bH, const void* __restrict__ Why,
    const void* __restrict__ by, void* __restrict__ out) {
  __shared__ __align__(16) float hrsh[NCELL * HS];
  __shared__ __align__(16) float xbuf[2 * NCELL * XG];
  __shared__ __align__(16) int sflags[32];
  __shared__ float fl;
  detect64((const unsigned short*)emb, threadIdx.x, &fl);
  __syncthreads();
  if (fl != 0.f)
    rec_body<__hip_bfloat16, PT>(pre, Whz0, bz0, Whr0, br0, WrH0, bH0, Wxz, Whz,
                                 bz, Wxr, Whr, br, WxH, WrH, bH, Why, by, out,
                                 hrsh, xbuf, sflags);
  else
    rec_body<float, PT>(pre, Whz0, bz0, Whr0, br0, WrH0, bH0, Wxz, Whz, bz, Wxr,
                        Whr, br, WxH, WrH, bH, Why, by, out, hrsh, xbuf, sflags);
}

// ---------------------------------------------------------------------------
template <typename PT>
static void launch_all(void* const* d_in, PT* pre, void* d_out, hipStream_t stream) {
  gru_pre<PT><<<B_ * S_ / 256, 256, 0, stream>>>(
      (const int*)d_in[0], d_in[1], d_in[2], d_in[5], d_in[8], pre);
  gru_rec<PT><<<B_ / GQ, TPBR, 0, stream>>>(
      d_in[1], pre, d_in[3], d_in[4], d_in[6], d_in[7], d_in[9], d_in[10],
      d_in[11], d_in[12], d_in[13], d_in[14], d_in[15], d_in[16], d_in[17],
      d_in[18], d_in[19], d_in[20], d_in[21], d_out);
}

extern "C" void kernel_launch(void* const* d_in, const int* in_sizes, int n_in,
                              void* d_out, int out_size, void* d_ws, size_t ws_size,
                              hipStream_t stream) {
  const size_t needF = (size_t)B_ * S_ * 24 * sizeof(float);
  if (ws_size >= needF)
    launch_all<float>(d_in, (float*)d_ws, d_out, stream);
  else
    launch_all<__hip_bfloat16>(d_in, (__hip_bfloat16*)d_ws, d_out, stream);
}